// Round 5
// baseline (329.884 us; speedup 1.0000x reference)
//
#include <hip/hip_runtime.h>
#include <math.h>

// Problem constants (fixed by reference setup_inputs)
#define TFRAMES 6
#define ZD 32
#define YD 512
#define XD 512
#define NRAYS 65536
#define NSTEPS 192          // 192 = 64 lanes * 3 steps/lane
#define VOXEL 0.2f

// Wave-per-ray differentiable volume rendering.
// Lane l handles steps 3l, 3l+1, 3l+2. Optical-thickness prefix via wave-wide
// inclusive scan (shfl_up); per-step weights via transmittance differences
// (exp(-cum_before) - exp(-cum_after)), which is exactly trans*alpha; expected
// termination distance reduced with a butterfly shfl_xor.
__global__ __launch_bounds__(256) void volrender_kernel(
    const float* __restrict__ sigma,   // [T,Z,Y,X]
    const float* __restrict__ org,     // [T,3]
    const float* __restrict__ pcd,     // [N,3]
    const int*   __restrict__ tindex,  // [N]
    float*       __restrict__ out)     // [2*N]: pred then gt
{
    const int lane = threadIdx.x & 63;
    const int ray  = (blockIdx.x * blockDim.x + threadIdx.x) >> 6;
    if (ray >= NRAYS) return;

    // Ray-uniform data (every lane loads same address -> HW broadcast)
    const int   t  = tindex[ray];
    const float px = pcd[ray * 3 + 0];
    const float py = pcd[ray * 3 + 1];
    const float pz = pcd[ray * 3 + 2];
    const float ox = org[t * 3 + 0];
    const float oy = org[t * 3 + 1];
    const float oz = org[t * 3 + 2];

    const float rx = px - ox, ry = py - oy, rz = pz - oz;
    float gt = sqrtf(rx * rx + ry * ry + rz * rz);
    const float invgt = 1.0f / fmaxf(gt, 1e-8f);
    const float dx = rx * invgt, dy = ry * invgt, dz = rz * invgt;
    const float delta = gt * (1.0f / NSTEPS);

    const int base = t * (ZD * YD * XD);

    float tau[3], tt[3];
#pragma unroll
    for (int j = 0; j < 3; ++j) {
        const int   s    = lane * 3 + j;
        const float frac = ((float)s + 0.5f) * (1.0f / NSTEPS);
        const float tcur = gt * frac;
        tt[j] = tcur;
        const float x = ox + dx * tcur;
        const float y = oy + dy * tcur;
        const float z = oz + dz * tcur;
        const int ix = (int)floorf(x);
        const int iy = (int)floorf(y);
        const int iz = (int)floorf(z);
        const bool inside = (ix >= 0) & (ix < XD) & (iy >= 0) & (iy < YD) &
                            (iz >= 0) & (iz < ZD);
        // clamp + always-load keeps the wave convergent (no divergent branch)
        const int ixc = min(max(ix, 0), XD - 1);
        const int iyc = min(max(iy, 0), YD - 1);
        const int izc = min(max(iz, 0), ZD - 1);
        const float sv = sigma[base + (izc * YD + iyc) * XD + ixc];
        tau[j] = inside ? sv * delta : 0.0f;
    }

    // Per-lane local prefix of the 3 taus
    const float p0 = tau[0];
    const float p1 = p0 + tau[1];
    const float p2 = p1 + tau[2];

    // Wave-wide inclusive scan of per-lane totals (p2)
    float incl = p2;
#pragma unroll
    for (int off = 1; off < 64; off <<= 1) {
        const float u = __shfl_up(incl, off);
        if (lane >= off) incl += u;
    }
    const float excl  = incl - p2;           // cum before this lane's steps
    const float total = __shfl(incl, 63);    // full-ray optical thickness

    // trans*alpha*t summed: (exp(-cum_before) - exp(-cum_after)) * t
    const float e0 = __expf(-excl);
    const float e1 = __expf(-(excl + p0));
    const float e2 = __expf(-(excl + p1));
    const float e3 = __expf(-(excl + p2));
    float pr = (e0 - e1) * tt[0] + (e1 - e2) * tt[1] + (e2 - e3) * tt[2];

    // Butterfly reduce across the wave
#pragma unroll
    for (int off = 32; off >= 1; off >>= 1)
        pr += __shfl_xor(pr, off);

    float pred = pr + __expf(-total) * gt;   // residual transmittance -> ray end

    // NaN/Inf cleanup (matches reference wrapper semantics)
    if (isnan(pred) || isinf(pred)) { pred = 0.0f; gt = 0.0f; }

    if (lane == 0) {
        out[ray]         = pred * VOXEL;
        out[NRAYS + ray] = gt * VOXEL;
    }
}

extern "C" void kernel_launch(void* const* d_in, const int* in_sizes, int n_in,
                              void* d_out, int out_size, void* d_ws, size_t ws_size,
                              hipStream_t stream) {
    const float* sigma  = (const float*)d_in[0];  // [1,6,32,512,512]
    const float* org    = (const float*)d_in[1];  // [1,6,3]
    const float* pcd    = (const float*)d_in[2];  // [1,65536,3]
    const int*   tindex = (const int*)d_in[3];    // [1,65536]
    float*       out    = (float*)d_out;          // [2*65536]

    // one wave (64 lanes) per ray; 256 threads/block = 4 rays/block
    const int threads = 256;
    const int blocks  = (NRAYS * 64) / threads;   // 16384
    volrender_kernel<<<blocks, threads, 0, stream>>>(sigma, org, pcd, tindex, out);
}